// Round 10
// baseline (286.206 us; speedup 1.0000x reference)
//
#include <hip/hip_runtime.h>
#include <math.h>

#define NB 16
#define NC 256
#define NN 4096
#define HD 32
#define BHD 128   // NB*NHD
#define KSPLIT 32
#define KRED 8    // partial groups after in-block 4-way reduction

typedef unsigned short bf16_t;
typedef __attribute__((ext_vector_type(4))) float floatx4;
typedef __attribute__((ext_vector_type(16))) float floatx16;
typedef __attribute__((ext_vector_type(8))) short shortx8;

__device__ __forceinline__ float bf2f(unsigned int u16) {
  return __uint_as_float(u16 << 16);
}
__device__ __forceinline__ bf16_t f2bf(float f) {
  unsigned int u = __float_as_uint(f);
  return (bf16_t)((u + 0x7FFFu + ((u >> 16) & 1u)) >> 16);
}
__device__ __forceinline__ float softplusf(float x) {
  return fmaxf(x, 0.0f) + log1pf(expf(-fabsf(x)));
}

// async global->LDS, 16B per lane; lds base must be wave-uniform
__device__ __forceinline__ void gl_lds16(const void* g, void* l) {
  __builtin_amdgcn_global_load_lds(
      (const __attribute__((address_space(1))) unsigned int*)g,
      (__attribute__((address_space(3))) unsigned int*)l, 16, 0, 0);
}

// ---------------------------------------------------------------------------
// prep: x [b][c][n] fp32 -> xbf [b][n][c] bf16 (transpose + cast)
// ---------------------------------------------------------------------------
__global__ __launch_bounds__(256) void k_prepx(
    const float* __restrict__ x, bf16_t* __restrict__ xbf)
{
  __shared__ float T[64][68];
  const int tid = threadIdx.x;
  const int n0 = blockIdx.x * 64, c0 = blockIdx.y * 64, b = blockIdx.z;
  const float* xb = x + (size_t)b * NC * NN;
#pragma unroll
  for (int it = 0; it < 4; ++it) {
    int c = it * 16 + (tid >> 4);
    int n4 = (tid & 15) * 4;
    float4 v = *(const float4*)(xb + (size_t)(c0 + c) * NN + n0 + n4);
    T[c][n4 + 0] = v.x; T[c][n4 + 1] = v.y;
    T[c][n4 + 2] = v.z; T[c][n4 + 3] = v.w;
  }
  __syncthreads();
  bf16_t* ob = xbf + (size_t)b * NN * NC;
#pragma unroll
  for (int it = 0; it < 2; ++it) {
    int n = it * 32 + (tid >> 3);
    int ch = (tid & 7) * 8;
    unsigned short e[8];
#pragma unroll
    for (int j = 0; j < 8; ++j) e[j] = f2bf(T[ch + j][n]);
    uint4 u;
    u.x = e[0] | ((unsigned)e[1] << 16); u.y = e[2] | ((unsigned)e[3] << 16);
    u.z = e[4] | ((unsigned)e[5] << 16); u.w = e[6] | ((unsigned)e[7] << 16);
    *(uint4*)(ob + (size_t)(n0 + n) * NC + c0 + ch) = u;
  }
}

// ---------------------------------------------------------------------------
// prep: pack weights to bf16, biases, and rscale[c] = 1/softplus(scale[c])
// ---------------------------------------------------------------------------
__global__ __launch_bounds__(256) void k_prepw(
    const float* __restrict__ Wq, const float* __restrict__ Wkv,
    const float* __restrict__ Wp, const float* __restrict__ bq,
    const float* __restrict__ bkv, const float* __restrict__ sp,
    bf16_t* __restrict__ Wqkvb, bf16_t* __restrict__ Wpb,
    float* __restrict__ bias768, float* __restrict__ rscale)
{
  const int blk = blockIdx.x;
  const int tid = threadIdx.x;
  if (blk < 768) {
    const float* src = (blk < 256) ? (Wq + (size_t)blk * NC)
                                   : (Wkv + (size_t)(blk - 256) * NC);
    Wqkvb[(size_t)blk * NC + tid] = f2bf(src[tid]);
  } else if (blk < 1024) {
    int j = blk - 768;
    Wpb[(size_t)j * NC + tid] = f2bf(Wp[(size_t)j * NC + tid]);
  } else if (blk == 1024) {
    for (int i = tid; i < 768; i += 256)
      bias768[i] = (i < 256) ? bq[i] : bkv[i - 256];
  } else {
    rscale[tid] = 1.0f / softplusf(sp[tid]);
  }
}

// ---------------------------------------------------------------------------
// Kernel 1: qkv projection via bf16 MFMA, 64x256 tile, BK=64 (r8 verified:
// 61.5us; r9's 2-phase dbuf regressed -> reverted). Focusing feature map
// fused (wave-local reduction). 128B-row XOR swizzle, conflict-free.
// ---------------------------------------------------------------------------
__global__ __launch_bounds__(256) void k_qkv_mfma(
    const bf16_t* __restrict__ xbf, const bf16_t* __restrict__ Wqkvb,
    const float* __restrict__ bias768, const float* __restrict__ rscale,
    bf16_t* __restrict__ qkv)
{
  __shared__ bf16_t As[64 * 64];    // 8 KB
  __shared__ bf16_t Bs[256 * 64];   // 32 KB
  const int tid = threadIdx.x;
  const int lane = tid & 63;
  const int w = tid >> 6;
  const int b = blockIdx.z;
  const int m0 = blockIdx.x * 64;
  const int n0b = blockIdx.y;                 // 0=q, 1=k, 2=v
  const bf16_t* Ab = xbf + ((size_t)b * NN + m0) * NC;
  const bf16_t* Bb = Wqkvb + (size_t)n0b * 256 * NC;

  const int rowi = lane >> 3;                   // row within 8-row stage instr
  const int schunk = ((lane & 7) ^ rowi) * 8;   // pre-swizzled source chunk
  const int fm = lane & 15;
  const int kg = lane >> 4;
  const int f7 = fm & 7;

  floatx4 acc[16];   // [tn]; this wave's 16 tokens x all 256 channels
#pragma unroll
  for (int i = 0; i < 16; ++i) {
    floatx4 z = {0.f, 0.f, 0.f, 0.f};
    acc[i] = z;
  }

  for (int k0 = 0; k0 < NC; k0 += 64) {
#pragma unroll
    for (int i = 0; i < 2; ++i)
      gl_lds16(Ab + (size_t)(w * 16 + i * 8 + rowi) * NC + k0 + schunk,
               &As[(w * 16 + i * 8) * 64]);
#pragma unroll
    for (int i = 0; i < 8; ++i)
      gl_lds16(Bb + (size_t)(w * 64 + i * 8 + rowi) * NC + k0 + schunk,
               &Bs[(w * 64 + i * 8) * 64]);
    __syncthreads();
#pragma unroll
    for (int h = 0; h < 2; ++h) {
      const int rofs = (((h << 2) | kg) ^ f7) * 8;
      shortx8 af = *(const shortx8*)&As[(w * 16 + fm) * 64 + rofs];
#pragma unroll
      for (int tn = 0; tn < 16; ++tn) {
        shortx8 bfrag = *(const shortx8*)&Bs[(tn * 16 + fm) * 64 + rofs];
        acc[tn] = __builtin_amdgcn_mfma_f32_16x16x32_bf16(af, bfrag, acc[tn], 0, 0, 0);
      }
    }
    __syncthreads();
  }

  bf16_t* obase = qkv + ((size_t)b * NN + m0) * 768 + n0b * 256;
  const int trow0 = w * 16 + kg * 4;   // first of this thread's 4 tokens

  if (n0b == 2) {
    // ---- v: bias + store (full 512B token rows per wave) ----
#pragma unroll
    for (int tn = 0; tn < 16; ++tn) {
      float bv = bias768[512 + tn * 16 + fm];
#pragma unroll
      for (int r = 0; r < 4; ++r)
        obase[(size_t)(trow0 + r) * 768 + tn * 16 + fm] =
            f2bf(acc[tn][r] + bv);
    }
  } else {
    // ---- q/k: fused focusing feature map, wave-local reduction ----
    float s2[4] = {0.f, 0.f, 0.f, 0.f};
    float s6[4] = {0.f, 0.f, 0.f, 0.f};
#pragma unroll
    for (int tn = 0; tn < 16; ++tn) {
      int ch = tn * 16 + fm;
      float bv = bias768[n0b * 256 + ch];
      float rsv = rscale[ch];
#pragma unroll
      for (int r = 0; r < 4; ++r) {
        float qi = (fmaxf(acc[tn][r] + bv, 0.f) + 1e-6f) * rsv;
        float q3 = qi * qi * qi;
        acc[tn][r] = q3;
        s2[r] += qi * qi;
        s6[r] += q3 * q3;
      }
    }
    // all-reduce over the 16 fm lanes (kg preserved -> token set preserved)
#pragma unroll
    for (int off = 1; off < 16; off <<= 1)
#pragma unroll
      for (int r = 0; r < 4; ++r) {
        s2[r] += __shfl_xor(s2[r], off);
        s6[r] += __shfl_xor(s6[r], off);
      }
    float qs[4];
#pragma unroll
    for (int r = 0; r < 4; ++r) qs[r] = sqrtf(s2[r]) * rsqrtf(s6[r]);
#pragma unroll
    for (int tn = 0; tn < 16; ++tn)
#pragma unroll
      for (int r = 0; r < 4; ++r)
        obase[(size_t)(trow0 + r) * 768 + tn * 16 + fm] =
            f2bf(acc[tn][r] * qs[r]);
  }
}

// ---------------------------------------------------------------------------
// Kernel 3: per-head kv_state (32x32) and k-sum via MFMA, LDS-free inner
// loop; 4-wave in-block LDS reduction -> one partial per block (KRED=8).
// ---------------------------------------------------------------------------
__global__ __launch_bounds__(256) void k_kvstate(
    const bf16_t* __restrict__ qkv, float* __restrict__ kvsp,
    float* __restrict__ ksump)
{
  __shared__ float red[4][1024];
  __shared__ float ksr[4][32];
  const int tid = threadIdx.x;
  const int lane = tid & 63;
  const int w = tid >> 6;
  const int bh = blockIdx.x;
  const int grp = blockIdx.y;               // 0..7 partial group
  const int spl = grp * 4 + w;              // 0..31, one split per wave
  const int b = bh >> 3, h = bh & 7;
  const int c = lane & 31;
  const int g = lane >> 5;

  floatx16 acc;
#pragma unroll
  for (int r = 0; r < 16; ++r) acc[r] = 0.f;
  float ksacc = 0.f;

  const bf16_t* kp = qkv + ((size_t)b * NN + (size_t)spl * (NN / KSPLIT) + g * 8) * 768
                     + 256 + h * HD + c;
#pragma unroll 2
  for (int s = 0; s < (NN / KSPLIT) / 16; ++s) {
    unsigned short av[8], bv[8];
#pragma unroll
    for (int e = 0; e < 8; ++e) {
      av[e] = kp[(size_t)e * 768];          // k[t0+g*8+e][c]
      bv[e] = kp[(size_t)e * 768 + 256];    // v[t0+g*8+e][d=c]
    }
    shortx8 af, bfg;
#pragma unroll
    for (int e = 0; e < 8; ++e) {
      af[e] = (short)av[e];
      bfg[e] = (short)bv[e];
      ksacc += bf2f(av[e]);
    }
    acc = __builtin_amdgcn_mfma_f32_32x32x16_bf16(af, bfg, acc, 0, 0, 0);
    kp += 16 * 768;
  }

  // park this wave's 32x32 tile in LDS
#pragma unroll
  for (int r = 0; r < 16; ++r) {
    int row = (r & 3) + 8 * (r >> 2) + 4 * g;
    red[w][row * 32 + c] = acc[r];
  }
  ksacc += __shfl_xor(ksacc, 32);
  if (g == 0) ksr[w][c] = ksacc;
  __syncthreads();

  // block-reduce 4 waves -> one fp32 partial
  const int p0 = tid * 4;
  float4 o;
  o.x = red[0][p0 + 0] + red[1][p0 + 0] + red[2][p0 + 0] + red[3][p0 + 0];
  o.y = red[0][p0 + 1] + red[1][p0 + 1] + red[2][p0 + 1] + red[3][p0 + 1];
  o.z = red[0][p0 + 2] + red[1][p0 + 2] + red[2][p0 + 2] + red[3][p0 + 2];
  o.w = red[0][p0 + 3] + red[1][p0 + 3] + red[2][p0 + 3] + red[3][p0 + 3];
  *(float4*)(kvsp + ((size_t)grp * BHD + bh) * (HD * HD) + p0) = o;
  if (tid < HD) {
    float u = ksr[0][tid] + ksr[1][tid] + ksr[2][tid] + ksr[3][tid];
    ksump[((size_t)grp * BHD + bh) * HD + tid] = u;
  }
}

// ---------------------------------------------------------------------------
// Kernel 4: combine KRED partials -> kvT bf16 [bh][d][c], ksumb bf16 [bh][c]
// ---------------------------------------------------------------------------
__global__ __launch_bounds__(256) void k_combine(
    const float* __restrict__ kvsp, const float* __restrict__ ksump,
    bf16_t* __restrict__ kvTb, bf16_t* __restrict__ ksumb)
{
  const int gid = blockIdx.x * 256 + threadIdx.x;  // 0..131071
  const int bh = gid >> 10;
  const int cd = gid & 1023;                       // c*32 + d
  const int cc = cd >> 5, d = cd & 31;
  float v = 0.f;
  const float* p = kvsp + (size_t)bh * (HD * HD) + cd;
#pragma unroll
  for (int s = 0; s < KRED; ++s) v += p[(size_t)s * BHD * (HD * HD)];
  kvTb[(size_t)bh * (HD * HD) + d * HD + cc] = f2bf(v);
  if (cd < HD) {
    float u = 0.f;
    const float* q = ksump + (size_t)bh * HD + cd;
#pragma unroll
    for (int s = 0; s < KRED; ++s) u += q[(size_t)s * BHD * HD];
    ksumb[(size_t)bh * HD + cd] = f2bf(u);
  }
}

// ---------------------------------------------------------------------------
// Kernel 5: attn = (q @ kv_state)*z + depthwise5x5(v) + dwc_b  (bf16 out)
// ---------------------------------------------------------------------------
#define VT_STRIDE 548   // bf16 per d-plane (68 cols * 8 ry = 544, pad->548)
__global__ __launch_bounds__(256) void k_attnout(
    const bf16_t* __restrict__ qkv, const bf16_t* __restrict__ kvTb,
    const bf16_t* __restrict__ ksumb, const float* __restrict__ dwc_w,
    const float* __restrict__ dwc_b, bf16_t* __restrict__ attn)
{
  __shared__ bf16_t vt[32 * VT_STRIDE];   // [d][col(68)][ry(8)]
  __shared__ bf16_t mvz[256 * 32];        // [token][d]
  const int tid = threadIdx.x;
  const int lane = tid & 63;
  const int w = tid >> 6;
  const int s = blockIdx.x;        // strip: rows 4s..4s+3
  const int bh = blockIdx.y;
  const int b = bh >> 3, h = bh & 7;

  // ---- stage v halo: rows y=4s-2+ry (ry 0..7), cols 0..63, 32 ch ----
#pragma unroll
  for (int it = 0; it < 8; ++it) {
    int idx = it * 256 + tid;          // 0..2047 = ry(8) x col(64) x slot(4)
    int ry = idx >> 8;
    int col = (idx >> 2) & 63;
    int slot = idx & 3;                // 8 ch each
    int y = s * 4 - 2 + ry;
    uint4 u = make_uint4(0u, 0u, 0u, 0u);
    if (y >= 0 && y < 64)
      u = *(const uint4*)(qkv + ((size_t)b * NN + y * 64 + col) * 768 + 512 + h * HD + slot * 8);
    unsigned short e[8];
    e[0] = (unsigned short)(u.x & 0xffffu); e[1] = (unsigned short)(u.x >> 16);
    e[2] = (unsigned short)(u.y & 0xffffu); e[3] = (unsigned short)(u.y >> 16);
    e[4] = (unsigned short)(u.z & 0xffffu); e[5] = (unsigned short)(u.z >> 16);
    e[6] = (unsigned short)(u.w & 0xffffu); e[7] = (unsigned short)(u.w >> 16);
#pragma unroll
    for (int j = 0; j < 8; ++j)
      vt[(slot * 8 + j) * VT_STRIDE + (col + 2) * 8 + ry] = e[j];
  }
  // zero halo cols cc in {0,1,66,67}: 32 d x 4 cc x 8 ry = 1024
#pragma unroll
  for (int e = 0; e < 4; ++e) {
    int idx = tid * 4 + e;             // 0..1023
    int d = idx >> 5;
    int rem = idx & 31;
    int cc4 = rem >> 3;                // 0..3
    int ry = rem & 7;
    int cc = (cc4 < 2) ? cc4 : (64 + cc4);
    vt[d * VT_STRIDE + cc * 8 + ry] = 0;
  }

  // ---- MFMA matvec: 16 m-tiles of 16 tokens; wave w handles 4 tiles ----
  const int fm = lane & 15;
  const int kg = lane >> 4;
  shortx8 b0 = *(const shortx8*)(kvTb + (size_t)bh * 1024 + fm * HD + kg * 8);
  shortx8 b1 = *(const shortx8*)(kvTb + (size_t)bh * 1024 + (16 + fm) * HD + kg * 8);
  shortx8 b2 = {0, 0, 0, 0, 0, 0, 0, 0};
  if (fm == 0) b2 = *(const shortx8*)(ksumb + (size_t)bh * HD + kg * 8);
  floatx4 zf = {0.f, 0.f, 0.f, 0.f};
#pragma unroll
  for (int q = 0; q < 4; ++q) {
    int mt = w * 4 + q;
    int tok = s * 256 + mt * 16 + fm;  // n within b
    shortx8 a = *(const shortx8*)(qkv + ((size_t)b * NN + tok) * 768 + h * HD + kg * 8);
    floatx4 d0 = __builtin_amdgcn_mfma_f32_16x16x32_bf16(a, b0, zf, 0, 0, 0);
    floatx4 d1 = __builtin_amdgcn_mfma_f32_16x16x32_bf16(a, b1, zf, 0, 0, 0);
    floatx4 d2 = __builtin_amdgcn_mfma_f32_16x16x32_bf16(a, b2, zf, 0, 0, 0);
#pragma unroll
    for (int r = 0; r < 4; ++r) {
      float qk = __shfl(d2[r], lane & 48);
      float z = 1.0f / (qk + 1e-6f);
      int tl = mt * 16 + kg * 4 + r;   // local token 0..255
      mvz[tl * 32 + fm] = f2bf(d0[r] * z);
      mvz[tl * 32 + 16 + fm] = f2bf(d1[r] * z);
    }
  }
  __syncthreads();

  // ---- conv + combine: thread = (d, xg); 8 x-cols x 4 ty ----
  const int d = tid & 31;
  const int xg = tid >> 5;
  const int x0c = xg * 8;
  float wr[25];
#pragma unroll
  for (int j = 0; j < 25; ++j) wr[j] = dwc_w[d * 25 + j];
  const float bd = dwc_b[d];
  const bf16_t* vd = vt + d * VT_STRIDE;

  float win[5][8];
#define LOADCOL(dst, cc) do {                                   \
    const bf16_t* _p = vd + (cc) * 8;                           \
    uint2 _u0 = *(const uint2*)_p;                              \
    uint2 _u1 = *(const uint2*)(_p + 4);                        \
    (dst)[0] = bf2f(_u0.x & 0xffffu); (dst)[1] = bf2f(_u0.x >> 16); \
    (dst)[2] = bf2f(_u0.y & 0xffffu); (dst)[3] = bf2f(_u0.y >> 16); \
    (dst)[4] = bf2f(_u1.x & 0xffffu); (dst)[5] = bf2f(_u1.x >> 16); \
    (dst)[6] = bf2f(_u1.y & 0xffffu); (dst)[7] = bf2f(_u1.y >> 16); \
  } while (0)

#pragma unroll
  for (int p = 0; p < 4; ++p) LOADCOL(win[p], x0c + p);

  bf16_t* arow = attn + ((size_t)b * NN + s * 256) * NC + h * HD + d;
#pragma unroll
  for (int i = 0; i < 8; ++i) {
    int x = x0c + i;
    LOADCOL(win[4], x + 4);
#pragma unroll
    for (int ty = 0; ty < 4; ++ty) {
      float acc = bd;
#pragma unroll
      for (int ky = 0; ky < 5; ++ky)
#pragma unroll
        for (int kx = 0; kx < 5; ++kx)
          acc += wr[ky * 5 + kx] * win[kx][ty + ky];
      int tl = ty * 64 + x;
      acc += bf2f(mvz[tl * 32 + d]);
      arow[(size_t)tl * NC] = f2bf(acc);
    }
#pragma unroll
    for (int c2 = 0; c2 < 4; ++c2)
#pragma unroll
      for (int r2 = 0; r2 < 8; ++r2) win[c2][r2] = win[c2 + 1][r2];
  }
#undef LOADCOL
}

// ---------------------------------------------------------------------------
// Kernel 6: output projection via bf16 MFMA, BK=64 (ported from qkv r8 win:
// halves barrier-drain count 16->8 per block). 128B-row XOR swizzle.
// fp32 transposed store epilogue unchanged (float4 token-contiguous).
// ---------------------------------------------------------------------------
__global__ __launch_bounds__(256) void k_proj_mfma(
    const bf16_t* __restrict__ attn, const bf16_t* __restrict__ Wpb,
    const float* __restrict__ bp, float* __restrict__ out)
{
  __shared__ bf16_t As[128 * 64];   // 16 KB
  __shared__ bf16_t Bs[128 * 64];   // 16 KB
  const int tid = threadIdx.x;
  const int lane = tid & 63;
  const int w = tid >> 6;
  const size_t m0 = (size_t)blockIdx.x * 128;
  const int n0 = blockIdx.y * 128;
  const bf16_t* Ab = attn + m0 * NC;
  const bf16_t* Bb = Wpb + (size_t)n0 * NC;

  const int wm = (w & 1) * 64;
  const int wn = (w >> 1) * 64;
  const int rowi = lane >> 3;                   // row within 8-row stage instr
  const int schunk = ((lane & 7) ^ rowi) * 8;   // pre-swizzled source chunk
  const int fm = lane & 15;
  const int kg = lane >> 4;
  const int f7 = fm & 7;

  floatx4 acc[4][4];
#pragma unroll
  for (int i = 0; i < 4; ++i)
#pragma unroll
    for (int j = 0; j < 4; ++j) {
      floatx4 z = {0.f, 0.f, 0.f, 0.f};
      acc[i][j] = z;
    }

  for (int k0 = 0; k0 < NC; k0 += 64) {
#pragma unroll
    for (int i = 0; i < 4; ++i) {
      gl_lds16(Ab + (size_t)(w * 32 + i * 8 + rowi) * NC + k0 + schunk,
               &As[(w * 32 + i * 8) * 64]);
      gl_lds16(Bb + (size_t)(w * 32 + i * 8 + rowi) * NC + k0 + schunk,
               &Bs[(w * 32 + i * 8) * 64]);
    }
    __syncthreads();
#pragma unroll
    for (int h = 0; h < 2; ++h) {
      const int rofs = (((h << 2) | kg) ^ f7) * 8;
      shortx8 af[4], bfg[4];
#pragma unroll
      for (int t = 0; t < 4; ++t) {
        af[t]  = *(const shortx8*)&As[(wm + t * 16 + fm) * 64 + rofs];
        bfg[t] = *(const shortx8*)&Bs[(wn + t * 16 + fm) * 64 + rofs];
      }
#pragma unroll
      for (int tm = 0; tm < 4; ++tm)
#pragma unroll
        for (int tn = 0; tn < 4; ++tn)
          acc[tm][tn] = __builtin_amdgcn_mfma_f32_16x16x32_bf16(
              af[tm], bfg[tn], acc[tm][tn], 0, 0, 0);
    }
    __syncthreads();
  }

  const int b = (int)(m0 >> 12);
  const int t0 = (int)(m0 & 4095);
  float* ob = out + (size_t)b * NC * NN;
#pragma unroll
  for (int tn = 0; tn < 4; ++tn) {
    int j = n0 + wn + tn * 16 + fm;
    float bj = bp[j];
#pragma unroll
    for (int tm = 0; tm < 4; ++tm) {
      int trow = t0 + wm + tm * 16 + kg * 4;
      float4 o;
      o.x = acc[tm][tn][0] + bj;
      o.y = acc[tm][tn][1] + bj;
      o.z = acc[tm][tn][2] + bj;
      o.w = acc[tm][tn][3] + bj;
      *(float4*)(ob + (size_t)j * NN + trow) = o;
    }
  }
}

// ---------------------------------------------------------------------------
extern "C" void kernel_launch(void* const* d_in, const int* in_sizes, int n_in,
                              void* d_out, int out_size, void* d_ws, size_t ws_size,
                              hipStream_t stream)
{
  (void)in_sizes; (void)n_in; (void)out_size; (void)ws_size;
  const float* x    = (const float*)d_in[0];
  const float* Wq   = (const float*)d_in[1];
  const float* bq   = (const float*)d_in[2];
  const float* Wkv  = (const float*)d_in[3];
  const float* bkv  = (const float*)d_in[4];
  const float* Wp   = (const float*)d_in[5];
  const float* bp   = (const float*)d_in[6];
  const float* dwcw = (const float*)d_in[7];
  const float* dwcb = (const float*)d_in[8];
  const float* sp   = (const float*)d_in[9];
  float* out = (float*)d_out;

  char* wsb = (char*)d_ws;
  bf16_t* qkv  = (bf16_t*)wsb;                            // 100,663,296 B
  bf16_t* attn = (bf16_t*)(wsb + 100663296u);             // 33,554,432 B
  bf16_t* xbf  = attn;                                    // alias (disjoint lifetimes)
  float*  kvsp  = (float*)attn;                           // 4,194,304 B (aliases attn)
  float*  ksump = (float*)(wsb + 100663296u + 16777216u); // 131,072 B
  char*   tail  = wsb + 100663296u + 33554432u + 2097152u + 65536u;
  bf16_t* kvTb  = (bf16_t*)tail;                          // 262,144 B
  bf16_t* ksumb = kvTb + (size_t)BHD * HD * HD;           // 8,192 B
  bf16_t* Wqkvb = ksumb + (size_t)BHD * HD;               // 393,216 B
  bf16_t* Wpb   = Wqkvb + 768 * 256;                      // 131,072 B
  float*  bias768 = (float*)(Wpb + 256 * 256);
  float*  rscale  = bias768 + 768;

  k_prepx<<<dim3(64, 4, 16), 256, 0, stream>>>(x, xbf);
  k_prepw<<<1026, 256, 0, stream>>>(Wq, Wkv, Wp, bq, bkv, sp, Wqkvb, Wpb, bias768, rscale);
  k_qkv_mfma<<<dim3(64, 3, 16), 256, 0, stream>>>(xbf, Wqkvb, bias768, rscale, qkv);
  k_kvstate<<<dim3(BHD, KRED), 256, 0, stream>>>(qkv, kvsp, ksump);
  k_combine<<<512, 256, 0, stream>>>(kvsp, ksump, kvTb, ksumb);
  k_attnout<<<dim3(16, BHD), 256, 0, stream>>>(qkv, kvTb, ksumb, dwcw, dwcb, attn);
  k_proj_mfma<<<dim3(512, 2), 256, 0, stream>>>(attn, Wpb, bp, out);
}

// Round 11
// 283.926 us; speedup vs baseline: 1.0080x; 1.0080x over previous
//
#include <hip/hip_runtime.h>
#include <math.h>

#define NB 16
#define NC 256
#define NN 4096
#define HD 32
#define BHD 128   // NB*NHD
#define KSPLIT 32
#define KRED 8    // partial groups after in-block 4-way reduction

typedef unsigned short bf16_t;
typedef __attribute__((ext_vector_type(4))) float floatx4;
typedef __attribute__((ext_vector_type(16))) float floatx16;
typedef __attribute__((ext_vector_type(8))) short shortx8;

__device__ __forceinline__ float bf2f(unsigned int u16) {
  return __uint_as_float(u16 << 16);
}
__device__ __forceinline__ bf16_t f2bf(float f) {
  unsigned int u = __float_as_uint(f);
  return (bf16_t)((u + 0x7FFFu + ((u >> 16) & 1u)) >> 16);
}
__device__ __forceinline__ float softplusf(float x) {
  return fmaxf(x, 0.0f) + log1pf(expf(-fabsf(x)));
}

// async global->LDS, 16B per lane; lds base must be wave-uniform
__device__ __forceinline__ void gl_lds16(const void* g, void* l) {
  __builtin_amdgcn_global_load_lds(
      (const __attribute__((address_space(1))) unsigned int*)g,
      (__attribute__((address_space(3))) unsigned int*)l, 16, 0, 0);
}

// ---------------------------------------------------------------------------
// prep: pack weights to bf16, biases, and rscale[c] = 1/softplus(scale[c])
// ---------------------------------------------------------------------------
__global__ __launch_bounds__(256) void k_prepw(
    const float* __restrict__ Wq, const float* __restrict__ Wkv,
    const float* __restrict__ Wp, const float* __restrict__ bq,
    const float* __restrict__ bkv, const float* __restrict__ sp,
    bf16_t* __restrict__ Wqkvb, bf16_t* __restrict__ Wpb,
    float* __restrict__ bias768, float* __restrict__ rscale)
{
  const int blk = blockIdx.x;
  const int tid = threadIdx.x;
  if (blk < 768) {
    const float* src = (blk < 256) ? (Wq + (size_t)blk * NC)
                                   : (Wkv + (size_t)(blk - 256) * NC);
    Wqkvb[(size_t)blk * NC + tid] = f2bf(src[tid]);
  } else if (blk < 1024) {
    int j = blk - 768;
    Wpb[(size_t)j * NC + tid] = f2bf(Wp[(size_t)j * NC + tid]);
  } else if (blk == 1024) {
    for (int i = tid; i < 768; i += 256)
      bias768[i] = (i < 256) ? bq[i] : bkv[i - 256];
  } else {
    rscale[tid] = 1.0f / softplusf(sp[tid]);
  }
}

// ---------------------------------------------------------------------------
// Kernel 1: qkv projection via bf16 MFMA, 64x256 tile, with the x-transpose
// FUSED (k_prepx + xbf eliminated). Per block: load x[b][ch][m0..m0+63] fp32
// once, transpose+cast into a RESIDENT swizzled A-tile (32KB LDS); K-loop
// (BK=32) stages only B via gl_lds into a 16KB buffer that time-shares LDS
// with the transpose scratch T (disjoint lifetimes). Focus fused (r7).
// ---------------------------------------------------------------------------
#define TST 76   // T row stride (bf16): 152B = 38 words, odd*2 -> 4-way max
__global__ __launch_bounds__(256) void k_qkv_mfma(
    const float* __restrict__ x, const bf16_t* __restrict__ Wqkvb,
    const float* __restrict__ bias768, const float* __restrict__ rscale,
    bf16_t* __restrict__ qkv)
{
  __shared__ bf16_t As[64 * 256];     // 32 KB resident A [tok][256ch], swizzled
  __shared__ uint4 uni4[1024];        // 16 KB union: T (prologue) / Bs (K-loop)
  bf16_t* T  = (bf16_t*)uni4;         // [64][TST]
  bf16_t* Bs = (bf16_t*)uni4;         // [256][32]

  const int tid = threadIdx.x;
  const int lane = tid & 63;
  const int w = tid >> 6;
  const int b = blockIdx.z;
  const int m0 = blockIdx.x * 64;
  const int n0b = blockIdx.y;                 // 0=q, 1=k, 2=v
  const float* xb = x + (size_t)b * NC * NN + m0;
  const bf16_t* Bb = Wqkvb + (size_t)n0b * 256 * NC;

  const int fm = lane & 15;
  const int kg = lane >> 4;

  // ---- prologue: transpose x -> As (4 groups of 64 channels) ----
  const int pa_ch = tid >> 2;                 // 0..63 channel within group
  const int pa_q4 = (tid & 3) * 16;           // token quarter
  const int pb_tok = tid & 63;
  const int pb_half = tid >> 6;               // 0..3 -> chunks 2h, 2h+1
#pragma unroll
  for (int g = 0; g < 4; ++g) {
    const float* src = xb + (size_t)(g * 64 + pa_ch) * NN + pa_q4;
#pragma unroll
    for (int i = 0; i < 4; ++i) {
      float4 v = *(const float4*)(src + i * 4);
      uint2 u;
      u.x = f2bf(v.x) | ((unsigned)f2bf(v.y) << 16);
      u.y = f2bf(v.z) | ((unsigned)f2bf(v.w) << 16);
      *(uint2*)&T[pa_ch * TST + pa_q4 + i * 4] = u;
    }
    __syncthreads();
#pragma unroll
    for (int c2 = 0; c2 < 2; ++c2) {
      int cw = pb_half * 2 + c2;              // chunk within group 0..7
      unsigned short e[8];
#pragma unroll
      for (int j = 0; j < 8; ++j) e[j] = T[(cw * 8 + j) * TST + pb_tok];
      uint4 u;
      u.x = e[0] | ((unsigned)e[1] << 16); u.y = e[2] | ((unsigned)e[3] << 16);
      u.z = e[4] | ((unsigned)e[5] << 16); u.w = e[6] | ((unsigned)e[7] << 16);
      int sgc = g * 8 + (cw ^ (pb_tok & 7));  // swizzled chunk index
      *(uint4*)&As[pb_tok * 256 + sgc * 8] = u;
    }
    __syncthreads();
  }

  // ---- K-loop: stage B only (BK=32), A resident ----
  const int srow = lane >> 2;
  const int scol = (((lane & 3) ^ ((lane >> 3) & 3))) * 8;  // r3 B swizzle
  const int kga = kg ^ ((fm >> 1) & 3);

  floatx4 acc[16];   // [tn]; this wave's 16 tokens x all 256 channels
#pragma unroll
  for (int i = 0; i < 16; ++i) {
    floatx4 z = {0.f, 0.f, 0.f, 0.f};
    acc[i] = z;
  }

  for (int t = 0; t < 8; ++t) {
    const int k0 = t * 32;
#pragma unroll
    for (int r = 0; r < 4; ++r)
      gl_lds16(Bb + (size_t)(w * 64 + r * 16 + srow) * NC + k0 + scol,
               &Bs[(w * 64 + r * 16) * 32]);
    __syncthreads();
    const int sgc = ((k0 >> 3) + kg) ^ (fm & 7);  // row&7 == fm&7
    shortx8 af = *(const shortx8*)&As[(w * 16 + fm) * 256 + sgc * 8];
#pragma unroll
    for (int tn = 0; tn < 16; ++tn) {
      shortx8 bfrag = *(const shortx8*)&Bs[(tn * 16 + fm) * 32 + kga * 8];
      acc[tn] = __builtin_amdgcn_mfma_f32_16x16x32_bf16(af, bfrag, acc[tn], 0, 0, 0);
    }
    __syncthreads();
  }

  bf16_t* obase = qkv + ((size_t)b * NN + m0) * 768 + n0b * 256;
  const int trow0 = w * 16 + kg * 4;   // first of this thread's 4 tokens

  if (n0b == 2) {
    // ---- v: bias + store (full 512B token rows per wave) ----
#pragma unroll
    for (int tn = 0; tn < 16; ++tn) {
      float bv = bias768[512 + tn * 16 + fm];
#pragma unroll
      for (int r = 0; r < 4; ++r)
        obase[(size_t)(trow0 + r) * 768 + tn * 16 + fm] =
            f2bf(acc[tn][r] + bv);
    }
  } else {
    // ---- q/k: fused focusing feature map, wave-local reduction ----
    float s2[4] = {0.f, 0.f, 0.f, 0.f};
    float s6[4] = {0.f, 0.f, 0.f, 0.f};
#pragma unroll
    for (int tn = 0; tn < 16; ++tn) {
      int ch = tn * 16 + fm;
      float bv = bias768[n0b * 256 + ch];
      float rsv = rscale[ch];
#pragma unroll
      for (int r = 0; r < 4; ++r) {
        float qi = (fmaxf(acc[tn][r] + bv, 0.f) + 1e-6f) * rsv;
        float q3 = qi * qi * qi;
        acc[tn][r] = q3;
        s2[r] += qi * qi;
        s6[r] += q3 * q3;
      }
    }
    // all-reduce over the 16 fm lanes (kg preserved -> token set preserved)
#pragma unroll
    for (int off = 1; off < 16; off <<= 1)
#pragma unroll
      for (int r = 0; r < 4; ++r) {
        s2[r] += __shfl_xor(s2[r], off);
        s6[r] += __shfl_xor(s6[r], off);
      }
    float qs[4];
#pragma unroll
    for (int r = 0; r < 4; ++r) qs[r] = sqrtf(s2[r]) * rsqrtf(s6[r]);
#pragma unroll
    for (int tn = 0; tn < 16; ++tn)
#pragma unroll
      for (int r = 0; r < 4; ++r)
        obase[(size_t)(trow0 + r) * 768 + tn * 16 + fm] =
            f2bf(acc[tn][r] * qs[r]);
  }
}

// ---------------------------------------------------------------------------
// Kernel 3: per-head kv_state (32x32) and k-sum via MFMA, LDS-free inner
// loop; 4-wave in-block LDS reduction -> one partial per block (KRED=8).
// ---------------------------------------------------------------------------
__global__ __launch_bounds__(256) void k_kvstate(
    const bf16_t* __restrict__ qkv, float* __restrict__ kvsp,
    float* __restrict__ ksump)
{
  __shared__ float red[4][1024];
  __shared__ float ksr[4][32];
  const int tid = threadIdx.x;
  const int lane = tid & 63;
  const int w = tid >> 6;
  const int bh = blockIdx.x;
  const int grp = blockIdx.y;               // 0..7 partial group
  const int spl = grp * 4 + w;              // 0..31, one split per wave
  const int b = bh >> 3, h = bh & 7;
  const int c = lane & 31;
  const int g = lane >> 5;

  floatx16 acc;
#pragma unroll
  for (int r = 0; r < 16; ++r) acc[r] = 0.f;
  float ksacc = 0.f;

  const bf16_t* kp = qkv + ((size_t)b * NN + (size_t)spl * (NN / KSPLIT) + g * 8) * 768
                     + 256 + h * HD + c;
#pragma unroll 2
  for (int s = 0; s < (NN / KSPLIT) / 16; ++s) {
    unsigned short av[8], bv[8];
#pragma unroll
    for (int e = 0; e < 8; ++e) {
      av[e] = kp[(size_t)e * 768];          // k[t0+g*8+e][c]
      bv[e] = kp[(size_t)e * 768 + 256];    // v[t0+g*8+e][d=c]
    }
    shortx8 af, bfg;
#pragma unroll
    for (int e = 0; e < 8; ++e) {
      af[e] = (short)av[e];
      bfg[e] = (short)bv[e];
      ksacc += bf2f(av[e]);
    }
    acc = __builtin_amdgcn_mfma_f32_32x32x16_bf16(af, bfg, acc, 0, 0, 0);
    kp += 16 * 768;
  }

  // park this wave's 32x32 tile in LDS
#pragma unroll
  for (int r = 0; r < 16; ++r) {
    int row = (r & 3) + 8 * (r >> 2) + 4 * g;
    red[w][row * 32 + c] = acc[r];
  }
  ksacc += __shfl_xor(ksacc, 32);
  if (g == 0) ksr[w][c] = ksacc;
  __syncthreads();

  // block-reduce 4 waves -> one fp32 partial
  const int p0 = tid * 4;
  float4 o;
  o.x = red[0][p0 + 0] + red[1][p0 + 0] + red[2][p0 + 0] + red[3][p0 + 0];
  o.y = red[0][p0 + 1] + red[1][p0 + 1] + red[2][p0 + 1] + red[3][p0 + 1];
  o.z = red[0][p0 + 2] + red[1][p0 + 2] + red[2][p0 + 2] + red[3][p0 + 2];
  o.w = red[0][p0 + 3] + red[1][p0 + 3] + red[2][p0 + 3] + red[3][p0 + 3];
  *(float4*)(kvsp + ((size_t)grp * BHD + bh) * (HD * HD) + p0) = o;
  if (tid < HD) {
    float u = ksr[0][tid] + ksr[1][tid] + ksr[2][tid] + ksr[3][tid];
    ksump[((size_t)grp * BHD + bh) * HD + tid] = u;
  }
}

// ---------------------------------------------------------------------------
// Kernel 4: combine KRED partials -> kvT bf16 [bh][d][c], ksumb bf16 [bh][c]
// ---------------------------------------------------------------------------
__global__ __launch_bounds__(256) void k_combine(
    const float* __restrict__ kvsp, const float* __restrict__ ksump,
    bf16_t* __restrict__ kvTb, bf16_t* __restrict__ ksumb)
{
  const int gid = blockIdx.x * 256 + threadIdx.x;  // 0..131071
  const int bh = gid >> 10;
  const int cd = gid & 1023;                       // c*32 + d
  const int cc = cd >> 5, d = cd & 31;
  float v = 0.f;
  const float* p = kvsp + (size_t)bh * (HD * HD) + cd;
#pragma unroll
  for (int s = 0; s < KRED; ++s) v += p[(size_t)s * BHD * (HD * HD)];
  kvTb[(size_t)bh * (HD * HD) + d * HD + cc] = f2bf(v);
  if (cd < HD) {
    float u = 0.f;
    const float* q = ksump + (size_t)bh * HD + cd;
#pragma unroll
    for (int s = 0; s < KRED; ++s) u += q[(size_t)s * BHD * HD];
    ksumb[(size_t)bh * HD + cd] = f2bf(u);
  }
}

// ---------------------------------------------------------------------------
// Kernel 5: attn = (q @ kv_state)*z + depthwise5x5(v) + dwc_b  (bf16 out)
// ---------------------------------------------------------------------------
#define VT_STRIDE 548   // bf16 per d-plane (68 cols * 8 ry = 544, pad->548)
__global__ __launch_bounds__(256) void k_attnout(
    const bf16_t* __restrict__ qkv, const bf16_t* __restrict__ kvTb,
    const bf16_t* __restrict__ ksumb, const float* __restrict__ dwc_w,
    const float* __restrict__ dwc_b, bf16_t* __restrict__ attn)
{
  __shared__ bf16_t vt[32 * VT_STRIDE];   // [d][col(68)][ry(8)]
  __shared__ bf16_t mvz[256 * 32];        // [token][d]
  const int tid = threadIdx.x;
  const int lane = tid & 63;
  const int w = tid >> 6;
  const int s = blockIdx.x;        // strip: rows 4s..4s+3
  const int bh = blockIdx.y;
  const int b = bh >> 3, h = bh & 7;

  // ---- stage v halo: rows y=4s-2+ry (ry 0..7), cols 0..63, 32 ch ----
#pragma unroll
  for (int it = 0; it < 8; ++it) {
    int idx = it * 256 + tid;          // 0..2047 = ry(8) x col(64) x slot(4)
    int ry = idx >> 8;
    int col = (idx >> 2) & 63;
    int slot = idx & 3;                // 8 ch each
    int y = s * 4 - 2 + ry;
    uint4 u = make_uint4(0u, 0u, 0u, 0u);
    if (y >= 0 && y < 64)
      u = *(const uint4*)(qkv + ((size_t)b * NN + y * 64 + col) * 768 + 512 + h * HD + slot * 8);
    unsigned short e[8];
    e[0] = (unsigned short)(u.x & 0xffffu); e[1] = (unsigned short)(u.x >> 16);
    e[2] = (unsigned short)(u.y & 0xffffu); e[3] = (unsigned short)(u.y >> 16);
    e[4] = (unsigned short)(u.z & 0xffffu); e[5] = (unsigned short)(u.z >> 16);
    e[6] = (unsigned short)(u.w & 0xffffu); e[7] = (unsigned short)(u.w >> 16);
#pragma unroll
    for (int j = 0; j < 8; ++j)
      vt[(slot * 8 + j) * VT_STRIDE + (col + 2) * 8 + ry] = e[j];
  }
  // zero halo cols cc in {0,1,66,67}: 32 d x 4 cc x 8 ry = 1024
#pragma unroll
  for (int e = 0; e < 4; ++e) {
    int idx = tid * 4 + e;             // 0..1023
    int d = idx >> 5;
    int rem = idx & 31;
    int cc4 = rem >> 3;                // 0..3
    int ry = rem & 7;
    int cc = (cc4 < 2) ? cc4 : (64 + cc4);
    vt[d * VT_STRIDE + cc * 8 + ry] = 0;
  }

  // ---- MFMA matvec: 16 m-tiles of 16 tokens; wave w handles 4 tiles ----
  const int fm = lane & 15;
  const int kg = lane >> 4;
  shortx8 b0 = *(const shortx8*)(kvTb + (size_t)bh * 1024 + fm * HD + kg * 8);
  shortx8 b1 = *(const shortx8*)(kvTb + (size_t)bh * 1024 + (16 + fm) * HD + kg * 8);
  shortx8 b2 = {0, 0, 0, 0, 0, 0, 0, 0};
  if (fm == 0) b2 = *(const shortx8*)(ksumb + (size_t)bh * HD + kg * 8);
  floatx4 zf = {0.f, 0.f, 0.f, 0.f};
#pragma unroll
  for (int q = 0; q < 4; ++q) {
    int mt = w * 4 + q;
    int tok = s * 256 + mt * 16 + fm;  // n within b
    shortx8 a = *(const shortx8*)(qkv + ((size_t)b * NN + tok) * 768 + h * HD + kg * 8);
    floatx4 d0 = __builtin_amdgcn_mfma_f32_16x16x32_bf16(a, b0, zf, 0, 0, 0);
    floatx4 d1 = __builtin_amdgcn_mfma_f32_16x16x32_bf16(a, b1, zf, 0, 0, 0);
    floatx4 d2 = __builtin_amdgcn_mfma_f32_16x16x32_bf16(a, b2, zf, 0, 0, 0);
#pragma unroll
    for (int r = 0; r < 4; ++r) {
      float qk = __shfl(d2[r], lane & 48);
      float z = 1.0f / (qk + 1e-6f);
      int tl = mt * 16 + kg * 4 + r;   // local token 0..255
      mvz[tl * 32 + fm] = f2bf(d0[r] * z);
      mvz[tl * 32 + 16 + fm] = f2bf(d1[r] * z);
    }
  }
  __syncthreads();

  // ---- conv + combine: thread = (d, xg); 8 x-cols x 4 ty ----
  const int d = tid & 31;
  const int xg = tid >> 5;
  const int x0c = xg * 8;
  float wr[25];
#pragma unroll
  for (int j = 0; j < 25; ++j) wr[j] = dwc_w[d * 25 + j];
  const float bd = dwc_b[d];
  const bf16_t* vd = vt + d * VT_STRIDE;

  float win[5][8];
#define LOADCOL(dst, cc) do {                                   \
    const bf16_t* _p = vd + (cc) * 8;                           \
    uint2 _u0 = *(const uint2*)_p;                              \
    uint2 _u1 = *(const uint2*)(_p + 4);                        \
    (dst)[0] = bf2f(_u0.x & 0xffffu); (dst)[1] = bf2f(_u0.x >> 16); \
    (dst)[2] = bf2f(_u0.y & 0xffffu); (dst)[3] = bf2f(_u0.y >> 16); \
    (dst)[4] = bf2f(_u1.x & 0xffffu); (dst)[5] = bf2f(_u1.x >> 16); \
    (dst)[6] = bf2f(_u1.y & 0xffffu); (dst)[7] = bf2f(_u1.y >> 16); \
  } while (0)

#pragma unroll
  for (int p = 0; p < 4; ++p) LOADCOL(win[p], x0c + p);

  bf16_t* arow = attn + ((size_t)b * NN + s * 256) * NC + h * HD + d;
#pragma unroll
  for (int i = 0; i < 8; ++i) {
    int x = x0c + i;
    LOADCOL(win[4], x + 4);
#pragma unroll
    for (int ty = 0; ty < 4; ++ty) {
      float acc = bd;
#pragma unroll
      for (int ky = 0; ky < 5; ++ky)
#pragma unroll
        for (int kx = 0; kx < 5; ++kx)
          acc += wr[ky * 5 + kx] * win[kx][ty + ky];
      int tl = ty * 64 + x;
      acc += bf2f(mvz[tl * 32 + d]);
      arow[(size_t)tl * NC] = f2bf(acc);
    }
#pragma unroll
    for (int c2 = 0; c2 < 4; ++c2)
#pragma unroll
      for (int r2 = 0; r2 < 8; ++r2) win[c2][r2] = win[c2 + 1][r2];
  }
#undef LOADCOL
}

// ---------------------------------------------------------------------------
// Kernel 6: output projection via bf16 MFMA, BK=64, 128B-row XOR swizzle.
// fp32 transposed store epilogue (float4 token-contiguous).
// ---------------------------------------------------------------------------
__global__ __launch_bounds__(256) void k_proj_mfma(
    const bf16_t* __restrict__ attn, const bf16_t* __restrict__ Wpb,
    const float* __restrict__ bp, float* __restrict__ out)
{
  __shared__ bf16_t As[128 * 64];   // 16 KB
  __shared__ bf16_t Bs[128 * 64];   // 16 KB
  const int tid = threadIdx.x;
  const int lane = tid & 63;
  const int w = tid >> 6;
  const size_t m0 = (size_t)blockIdx.x * 128;
  const int n0 = blockIdx.y * 128;
  const bf16_t* Ab = attn + m0 * NC;
  const bf16_t* Bb = Wpb + (size_t)n0 * NC;

  const int wm = (w & 1) * 64;
  const int wn = (w >> 1) * 64;
  const int rowi = lane >> 3;                   // row within 8-row stage instr
  const int schunk = ((lane & 7) ^ rowi) * 8;   // pre-swizzled source chunk
  const int fm = lane & 15;
  const int kg = lane >> 4;
  const int f7 = fm & 7;

  floatx4 acc[4][4];
#pragma unroll
  for (int i = 0; i < 4; ++i)
#pragma unroll
    for (int j = 0; j < 4; ++j) {
      floatx4 z = {0.f, 0.f, 0.f, 0.f};
      acc[i][j] = z;
    }

  for (int k0 = 0; k0 < NC; k0 += 64) {
#pragma unroll
    for (int i = 0; i < 4; ++i) {
      gl_lds16(Ab + (size_t)(w * 32 + i * 8 + rowi) * NC + k0 + schunk,
               &As[(w * 32 + i * 8) * 64]);
      gl_lds16(Bb + (size_t)(w * 32 + i * 8 + rowi) * NC + k0 + schunk,
               &Bs[(w * 32 + i * 8) * 64]);
    }
    __syncthreads();
#pragma unroll
    for (int h = 0; h < 2; ++h) {
      const int rofs = (((h << 2) | kg) ^ f7) * 8;
      shortx8 af[4], bfg[4];
#pragma unroll
      for (int t = 0; t < 4; ++t) {
        af[t]  = *(const shortx8*)&As[(wm + t * 16 + fm) * 64 + rofs];
        bfg[t] = *(const shortx8*)&Bs[(wn + t * 16 + fm) * 64 + rofs];
      }
#pragma unroll
      for (int tm = 0; tm < 4; ++tm)
#pragma unroll
        for (int tn = 0; tn < 4; ++tn)
          acc[tm][tn] = __builtin_amdgcn_mfma_f32_16x16x32_bf16(
              af[tm], bfg[tn], acc[tm][tn], 0, 0, 0);
    }
    __syncthreads();
  }

  const int b = (int)(m0 >> 12);
  const int t0 = (int)(m0 & 4095);
  float* ob = out + (size_t)b * NC * NN;
#pragma unroll
  for (int tn = 0; tn < 4; ++tn) {
    int j = n0 + wn + tn * 16 + fm;
    float bj = bp[j];
#pragma unroll
    for (int tm = 0; tm < 4; ++tm) {
      int trow = t0 + wm + tm * 16 + kg * 4;
      float4 o;
      o.x = acc[tm][tn][0] + bj;
      o.y = acc[tm][tn][1] + bj;
      o.z = acc[tm][tn][2] + bj;
      o.w = acc[tm][tn][3] + bj;
      *(float4*)(ob + (size_t)j * NN + trow) = o;
    }
  }
}

// ---------------------------------------------------------------------------
extern "C" void kernel_launch(void* const* d_in, const int* in_sizes, int n_in,
                              void* d_out, int out_size, void* d_ws, size_t ws_size,
                              hipStream_t stream)
{
  (void)in_sizes; (void)n_in; (void)out_size; (void)ws_size;
  const float* x    = (const float*)d_in[0];
  const float* Wq   = (const float*)d_in[1];
  const float* bq   = (const float*)d_in[2];
  const float* Wkv  = (const float*)d_in[3];
  const float* bkv  = (const float*)d_in[4];
  const float* Wp   = (const float*)d_in[5];
  const float* bp   = (const float*)d_in[6];
  const float* dwcw = (const float*)d_in[7];
  const float* dwcb = (const float*)d_in[8];
  const float* sp   = (const float*)d_in[9];
  float* out = (float*)d_out;

  char* wsb = (char*)d_ws;
  bf16_t* qkv  = (bf16_t*)wsb;                            // 100,663,296 B
  bf16_t* attn = (bf16_t*)(wsb + 100663296u);             // 33,554,432 B
  float*  kvsp  = (float*)attn;                           // 4,194,304 B (aliases attn)
  float*  ksump = (float*)(wsb + 100663296u + 16777216u); // 131,072 B
  char*   tail  = wsb + 100663296u + 33554432u + 2097152u + 65536u;
  bf16_t* kvTb  = (bf16_t*)tail;                          // 262,144 B
  bf16_t* ksumb = kvTb + (size_t)BHD * HD * HD;           // 8,192 B
  bf16_t* Wqkvb = ksumb + (size_t)BHD * HD;               // 393,216 B
  bf16_t* Wpb   = Wqkvb + 768 * 256;                      // 131,072 B
  float*  bias768 = (float*)(Wpb + 256 * 256);
  float*  rscale  = bias768 + 768;

  k_prepw<<<1026, 256, 0, stream>>>(Wq, Wkv, Wp, bq, bkv, sp, Wqkvb, Wpb, bias768, rscale);
  k_qkv_mfma<<<dim3(64, 3, 16), 256, 0, stream>>>(x, Wqkvb, bias768, rscale, qkv);
  k_kvstate<<<dim3(BHD, KRED), 256, 0, stream>>>(qkv, kvsp, ksump);
  k_combine<<<512, 256, 0, stream>>>(kvsp, ksump, kvTb, ksumb);
  k_attnout<<<dim3(16, BHD), 256, 0, stream>>>(qkv, kvTb, ksumb, dwcw, dwcb, attn);
  k_proj_mfma<<<dim3(512, 2), 256, 0, stream>>>(attn, Wpb, bp, out);
}

// Round 12
// 271.662 us; speedup vs baseline: 1.0535x; 1.0451x over previous
//
#include <hip/hip_runtime.h>
#include <math.h>

#define NB 16
#define NC 256
#define NN 4096
#define HD 32
#define BHD 128   // NB*NHD
#define KSPLIT 32
#define KRED 8    // partial groups after in-block 4-way reduction

typedef unsigned short bf16_t;
typedef __attribute__((ext_vector_type(4))) float floatx4;
typedef __attribute__((ext_vector_type(16))) float floatx16;
typedef __attribute__((ext_vector_type(8))) short shortx8;

__device__ __forceinline__ float bf2f(unsigned int u16) {
  return __uint_as_float(u16 << 16);
}
__device__ __forceinline__ bf16_t f2bf(float f) {
  unsigned int u = __float_as_uint(f);
  return (bf16_t)((u + 0x7FFFu + ((u >> 16) & 1u)) >> 16);
}
__device__ __forceinline__ float softplusf(float x) {
  return fmaxf(x, 0.0f) + log1pf(expf(-fabsf(x)));
}

// async global->LDS, 16B per lane; lds base must be wave-uniform
__device__ __forceinline__ void gl_lds16(const void* g, void* l) {
  __builtin_amdgcn_global_load_lds(
      (const __attribute__((address_space(1))) unsigned int*)g,
      (__attribute__((address_space(3))) unsigned int*)l, 16, 0, 0);
}

// ---------------------------------------------------------------------------
// prep: x [b][c][n] fp32 -> xbf [b][n][c] bf16 (transpose + cast)
// ---------------------------------------------------------------------------
__global__ __launch_bounds__(256) void k_prepx(
    const float* __restrict__ x, bf16_t* __restrict__ xbf)
{
  __shared__ float T[64][68];
  const int tid = threadIdx.x;
  const int n0 = blockIdx.x * 64, c0 = blockIdx.y * 64, b = blockIdx.z;
  const float* xb = x + (size_t)b * NC * NN;
#pragma unroll
  for (int it = 0; it < 4; ++it) {
    int c = it * 16 + (tid >> 4);
    int n4 = (tid & 15) * 4;
    float4 v = *(const float4*)(xb + (size_t)(c0 + c) * NN + n0 + n4);
    T[c][n4 + 0] = v.x; T[c][n4 + 1] = v.y;
    T[c][n4 + 2] = v.z; T[c][n4 + 3] = v.w;
  }
  __syncthreads();
  bf16_t* ob = xbf + (size_t)b * NN * NC;
#pragma unroll
  for (int it = 0; it < 2; ++it) {
    int n = it * 32 + (tid >> 3);
    int ch = (tid & 7) * 8;
    unsigned short e[8];
#pragma unroll
    for (int j = 0; j < 8; ++j) e[j] = f2bf(T[ch + j][n]);
    uint4 u;
    u.x = e[0] | ((unsigned)e[1] << 16); u.y = e[2] | ((unsigned)e[3] << 16);
    u.z = e[4] | ((unsigned)e[5] << 16); u.w = e[6] | ((unsigned)e[7] << 16);
    *(uint4*)(ob + (size_t)(n0 + n) * NC + c0 + ch) = u;
  }
}

// ---------------------------------------------------------------------------
// prep: pack weights to bf16, biases, and rscale[c] = 1/softplus(scale[c])
// ---------------------------------------------------------------------------
__global__ __launch_bounds__(256) void k_prepw(
    const float* __restrict__ Wq, const float* __restrict__ Wkv,
    const float* __restrict__ Wp, const float* __restrict__ bq,
    const float* __restrict__ bkv, const float* __restrict__ sp,
    bf16_t* __restrict__ Wqkvb, bf16_t* __restrict__ Wpb,
    float* __restrict__ bias768, float* __restrict__ rscale)
{
  const int blk = blockIdx.x;
  const int tid = threadIdx.x;
  if (blk < 768) {
    const float* src = (blk < 256) ? (Wq + (size_t)blk * NC)
                                   : (Wkv + (size_t)(blk - 256) * NC);
    Wqkvb[(size_t)blk * NC + tid] = f2bf(src[tid]);
  } else if (blk < 1024) {
    int j = blk - 768;
    Wpb[(size_t)j * NC + tid] = f2bf(Wp[(size_t)j * NC + tid]);
  } else if (blk == 1024) {
    for (int i = tid; i < 768; i += 256)
      bias768[i] = (i < 256) ? bq[i] : bkv[i - 256];
  } else {
    rscale[tid] = 1.0f / softplusf(sp[tid]);
  }
}

// ---------------------------------------------------------------------------
// Kernel 1: qkv projection via bf16 MFMA, 64x256 tile, BK=64 (r8 verified:
// 61.5us; r9 dbuf and r11 prepx-fusion both regressed -> reverted to r8).
// Focusing feature map fused (wave-local reduction). 128B-row XOR swizzle.
// ---------------------------------------------------------------------------
__global__ __launch_bounds__(256) void k_qkv_mfma(
    const bf16_t* __restrict__ xbf, const bf16_t* __restrict__ Wqkvb,
    const float* __restrict__ bias768, const float* __restrict__ rscale,
    bf16_t* __restrict__ qkv)
{
  __shared__ bf16_t As[64 * 64];    // 8 KB
  __shared__ bf16_t Bs[256 * 64];   // 32 KB
  const int tid = threadIdx.x;
  const int lane = tid & 63;
  const int w = tid >> 6;
  const int b = blockIdx.z;
  const int m0 = blockIdx.x * 64;
  const int n0b = blockIdx.y;                 // 0=q, 1=k, 2=v
  const bf16_t* Ab = xbf + ((size_t)b * NN + m0) * NC;
  const bf16_t* Bb = Wqkvb + (size_t)n0b * 256 * NC;

  const int rowi = lane >> 3;                   // row within 8-row stage instr
  const int schunk = ((lane & 7) ^ rowi) * 8;   // pre-swizzled source chunk
  const int fm = lane & 15;
  const int kg = lane >> 4;
  const int f7 = fm & 7;

  floatx4 acc[16];   // [tn]; this wave's 16 tokens x all 256 channels
#pragma unroll
  for (int i = 0; i < 16; ++i) {
    floatx4 z = {0.f, 0.f, 0.f, 0.f};
    acc[i] = z;
  }

  for (int k0 = 0; k0 < NC; k0 += 64) {
#pragma unroll
    for (int i = 0; i < 2; ++i)
      gl_lds16(Ab + (size_t)(w * 16 + i * 8 + rowi) * NC + k0 + schunk,
               &As[(w * 16 + i * 8) * 64]);
#pragma unroll
    for (int i = 0; i < 8; ++i)
      gl_lds16(Bb + (size_t)(w * 64 + i * 8 + rowi) * NC + k0 + schunk,
               &Bs[(w * 64 + i * 8) * 64]);
    __syncthreads();
#pragma unroll
    for (int h = 0; h < 2; ++h) {
      const int rofs = (((h << 2) | kg) ^ f7) * 8;
      shortx8 af = *(const shortx8*)&As[(w * 16 + fm) * 64 + rofs];
#pragma unroll
      for (int tn = 0; tn < 16; ++tn) {
        shortx8 bfrag = *(const shortx8*)&Bs[(tn * 16 + fm) * 64 + rofs];
        acc[tn] = __builtin_amdgcn_mfma_f32_16x16x32_bf16(af, bfrag, acc[tn], 0, 0, 0);
      }
    }
    __syncthreads();
  }

  bf16_t* obase = qkv + ((size_t)b * NN + m0) * 768 + n0b * 256;
  const int trow0 = w * 16 + kg * 4;   // first of this thread's 4 tokens

  if (n0b == 2) {
    // ---- v: bias + store (full 512B token rows per wave) ----
#pragma unroll
    for (int tn = 0; tn < 16; ++tn) {
      float bv = bias768[512 + tn * 16 + fm];
#pragma unroll
      for (int r = 0; r < 4; ++r)
        obase[(size_t)(trow0 + r) * 768 + tn * 16 + fm] =
            f2bf(acc[tn][r] + bv);
    }
  } else {
    // ---- q/k: fused focusing feature map, wave-local reduction ----
    float s2[4] = {0.f, 0.f, 0.f, 0.f};
    float s6[4] = {0.f, 0.f, 0.f, 0.f};
#pragma unroll
    for (int tn = 0; tn < 16; ++tn) {
      int ch = tn * 16 + fm;
      float bv = bias768[n0b * 256 + ch];
      float rsv = rscale[ch];
#pragma unroll
      for (int r = 0; r < 4; ++r) {
        float qi = (fmaxf(acc[tn][r] + bv, 0.f) + 1e-6f) * rsv;
        float q3 = qi * qi * qi;
        acc[tn][r] = q3;
        s2[r] += qi * qi;
        s6[r] += q3 * q3;
      }
    }
    // all-reduce over the 16 fm lanes (kg preserved -> token set preserved)
#pragma unroll
    for (int off = 1; off < 16; off <<= 1)
#pragma unroll
      for (int r = 0; r < 4; ++r) {
        s2[r] += __shfl_xor(s2[r], off);
        s6[r] += __shfl_xor(s6[r], off);
      }
    float qs[4];
#pragma unroll
    for (int r = 0; r < 4; ++r) qs[r] = sqrtf(s2[r]) * rsqrtf(s6[r]);
#pragma unroll
    for (int tn = 0; tn < 16; ++tn)
#pragma unroll
      for (int r = 0; r < 4; ++r)
        obase[(size_t)(trow0 + r) * 768 + tn * 16 + fm] =
            f2bf(acc[tn][r] * qs[r]);
  }
}

// ---------------------------------------------------------------------------
// Kernel 3: per-head kv_state (32x32) and k-sum via MFMA, LDS-free inner
// loop; 4-wave in-block LDS reduction -> one partial per block (KRED=8).
// ---------------------------------------------------------------------------
__global__ __launch_bounds__(256) void k_kvstate(
    const bf16_t* __restrict__ qkv, float* __restrict__ kvsp,
    float* __restrict__ ksump)
{
  __shared__ float red[4][1024];
  __shared__ float ksr[4][32];
  const int tid = threadIdx.x;
  const int lane = tid & 63;
  const int w = tid >> 6;
  const int bh = blockIdx.x;
  const int grp = blockIdx.y;               // 0..7 partial group
  const int spl = grp * 4 + w;              // 0..31, one split per wave
  const int b = bh >> 3, h = bh & 7;
  const int c = lane & 31;
  const int g = lane >> 5;

  floatx16 acc;
#pragma unroll
  for (int r = 0; r < 16; ++r) acc[r] = 0.f;
  float ksacc = 0.f;

  const bf16_t* kp = qkv + ((size_t)b * NN + (size_t)spl * (NN / KSPLIT) + g * 8) * 768
                     + 256 + h * HD + c;
#pragma unroll 2
  for (int s = 0; s < (NN / KSPLIT) / 16; ++s) {
    unsigned short av[8], bv[8];
#pragma unroll
    for (int e = 0; e < 8; ++e) {
      av[e] = kp[(size_t)e * 768];          // k[t0+g*8+e][c]
      bv[e] = kp[(size_t)e * 768 + 256];    // v[t0+g*8+e][d=c]
    }
    shortx8 af, bfg;
#pragma unroll
    for (int e = 0; e < 8; ++e) {
      af[e] = (short)av[e];
      bfg[e] = (short)bv[e];
      ksacc += bf2f(av[e]);
    }
    acc = __builtin_amdgcn_mfma_f32_32x32x16_bf16(af, bfg, acc, 0, 0, 0);
    kp += 16 * 768;
  }

  // park this wave's 32x32 tile in LDS
#pragma unroll
  for (int r = 0; r < 16; ++r) {
    int row = (r & 3) + 8 * (r >> 2) + 4 * g;
    red[w][row * 32 + c] = acc[r];
  }
  ksacc += __shfl_xor(ksacc, 32);
  if (g == 0) ksr[w][c] = ksacc;
  __syncthreads();

  // block-reduce 4 waves -> one fp32 partial
  const int p0 = tid * 4;
  float4 o;
  o.x = red[0][p0 + 0] + red[1][p0 + 0] + red[2][p0 + 0] + red[3][p0 + 0];
  o.y = red[0][p0 + 1] + red[1][p0 + 1] + red[2][p0 + 1] + red[3][p0 + 1];
  o.z = red[0][p0 + 2] + red[1][p0 + 2] + red[2][p0 + 2] + red[3][p0 + 2];
  o.w = red[0][p0 + 3] + red[1][p0 + 3] + red[2][p0 + 3] + red[3][p0 + 3];
  *(float4*)(kvsp + ((size_t)grp * BHD + bh) * (HD * HD) + p0) = o;
  if (tid < HD) {
    float u = ksr[0][tid] + ksr[1][tid] + ksr[2][tid] + ksr[3][tid];
    ksump[((size_t)grp * BHD + bh) * HD + tid] = u;
  }
}

// ---------------------------------------------------------------------------
// Kernel 4: combine KRED partials -> kvT bf16 [bh][d][c], ksumb bf16 [bh][c]
// ---------------------------------------------------------------------------
__global__ __launch_bounds__(256) void k_combine(
    const float* __restrict__ kvsp, const float* __restrict__ ksump,
    bf16_t* __restrict__ kvTb, bf16_t* __restrict__ ksumb)
{
  const int gid = blockIdx.x * 256 + threadIdx.x;  // 0..131071
  const int bh = gid >> 10;
  const int cd = gid & 1023;                       // c*32 + d
  const int cc = cd >> 5, d = cd & 31;
  float v = 0.f;
  const float* p = kvsp + (size_t)bh * (HD * HD) + cd;
#pragma unroll
  for (int s = 0; s < KRED; ++s) v += p[(size_t)s * BHD * (HD * HD)];
  kvTb[(size_t)bh * (HD * HD) + d * HD + cc] = f2bf(v);
  if (cd < HD) {
    float u = 0.f;
    const float* q = ksump + (size_t)bh * HD + cd;
#pragma unroll
    for (int s = 0; s < KRED; ++s) u += q[(size_t)s * BHD * HD];
    ksumb[(size_t)bh * HD + cd] = f2bf(u);
  }
}

// ---------------------------------------------------------------------------
// Kernel 5: attn = (q @ kv_state)*z + depthwise5x5(v) + dwc_b  (bf16 out)
// ---------------------------------------------------------------------------
#define VT_STRIDE 548   // bf16 per d-plane (68 cols * 8 ry = 544, pad->548)
__global__ __launch_bounds__(256) void k_attnout(
    const bf16_t* __restrict__ qkv, const bf16_t* __restrict__ kvTb,
    const bf16_t* __restrict__ ksumb, const float* __restrict__ dwc_w,
    const float* __restrict__ dwc_b, bf16_t* __restrict__ attn)
{
  __shared__ bf16_t vt[32 * VT_STRIDE];   // [d][col(68)][ry(8)]
  __shared__ bf16_t mvz[256 * 32];        // [token][d]
  const int tid = threadIdx.x;
  const int lane = tid & 63;
  const int w = tid >> 6;
  const int s = blockIdx.x;        // strip: rows 4s..4s+3
  const int bh = blockIdx.y;
  const int b = bh >> 3, h = bh & 7;

  // ---- stage v halo: rows y=4s-2+ry (ry 0..7), cols 0..63, 32 ch ----
#pragma unroll
  for (int it = 0; it < 8; ++it) {
    int idx = it * 256 + tid;          // 0..2047 = ry(8) x col(64) x slot(4)
    int ry = idx >> 8;
    int col = (idx >> 2) & 63;
    int slot = idx & 3;                // 8 ch each
    int y = s * 4 - 2 + ry;
    uint4 u = make_uint4(0u, 0u, 0u, 0u);
    if (y >= 0 && y < 64)
      u = *(const uint4*)(qkv + ((size_t)b * NN + y * 64 + col) * 768 + 512 + h * HD + slot * 8);
    unsigned short e[8];
    e[0] = (unsigned short)(u.x & 0xffffu); e[1] = (unsigned short)(u.x >> 16);
    e[2] = (unsigned short)(u.y & 0xffffu); e[3] = (unsigned short)(u.y >> 16);
    e[4] = (unsigned short)(u.z & 0xffffu); e[5] = (unsigned short)(u.z >> 16);
    e[6] = (unsigned short)(u.w & 0xffffu); e[7] = (unsigned short)(u.w >> 16);
#pragma unroll
    for (int j = 0; j < 8; ++j)
      vt[(slot * 8 + j) * VT_STRIDE + (col + 2) * 8 + ry] = e[j];
  }
  // zero halo cols cc in {0,1,66,67}: 32 d x 4 cc x 8 ry = 1024
#pragma unroll
  for (int e = 0; e < 4; ++e) {
    int idx = tid * 4 + e;             // 0..1023
    int d = idx >> 5;
    int rem = idx & 31;
    int cc4 = rem >> 3;                // 0..3
    int ry = rem & 7;
    int cc = (cc4 < 2) ? cc4 : (64 + cc4);
    vt[d * VT_STRIDE + cc * 8 + ry] = 0;
  }

  // ---- MFMA matvec: 16 m-tiles of 16 tokens; wave w handles 4 tiles ----
  const int fm = lane & 15;
  const int kg = lane >> 4;
  shortx8 b0 = *(const shortx8*)(kvTb + (size_t)bh * 1024 + fm * HD + kg * 8);
  shortx8 b1 = *(const shortx8*)(kvTb + (size_t)bh * 1024 + (16 + fm) * HD + kg * 8);
  shortx8 b2 = {0, 0, 0, 0, 0, 0, 0, 0};
  if (fm == 0) b2 = *(const shortx8*)(ksumb + (size_t)bh * HD + kg * 8);
  floatx4 zf = {0.f, 0.f, 0.f, 0.f};
#pragma unroll
  for (int q = 0; q < 4; ++q) {
    int mt = w * 4 + q;
    int tok = s * 256 + mt * 16 + fm;  // n within b
    shortx8 a = *(const shortx8*)(qkv + ((size_t)b * NN + tok) * 768 + h * HD + kg * 8);
    floatx4 d0 = __builtin_amdgcn_mfma_f32_16x16x32_bf16(a, b0, zf, 0, 0, 0);
    floatx4 d1 = __builtin_amdgcn_mfma_f32_16x16x32_bf16(a, b1, zf, 0, 0, 0);
    floatx4 d2 = __builtin_amdgcn_mfma_f32_16x16x32_bf16(a, b2, zf, 0, 0, 0);
#pragma unroll
    for (int r = 0; r < 4; ++r) {
      float qk = __shfl(d2[r], lane & 48);
      float z = 1.0f / (qk + 1e-6f);
      int tl = mt * 16 + kg * 4 + r;   // local token 0..255
      mvz[tl * 32 + fm] = f2bf(d0[r] * z);
      mvz[tl * 32 + 16 + fm] = f2bf(d1[r] * z);
    }
  }
  __syncthreads();

  // ---- conv + combine: thread = (d, xg); 8 x-cols x 4 ty ----
  const int d = tid & 31;
  const int xg = tid >> 5;
  const int x0c = xg * 8;
  float wr[25];
#pragma unroll
  for (int j = 0; j < 25; ++j) wr[j] = dwc_w[d * 25 + j];
  const float bd = dwc_b[d];
  const bf16_t* vd = vt + d * VT_STRIDE;

  float win[5][8];
#define LOADCOL(dst, cc) do {                                   \
    const bf16_t* _p = vd + (cc) * 8;                           \
    uint2 _u0 = *(const uint2*)_p;                              \
    uint2 _u1 = *(const uint2*)(_p + 4);                        \
    (dst)[0] = bf2f(_u0.x & 0xffffu); (dst)[1] = bf2f(_u0.x >> 16); \
    (dst)[2] = bf2f(_u0.y & 0xffffu); (dst)[3] = bf2f(_u0.y >> 16); \
    (dst)[4] = bf2f(_u1.x & 0xffffu); (dst)[5] = bf2f(_u1.x >> 16); \
    (dst)[6] = bf2f(_u1.y & 0xffffu); (dst)[7] = bf2f(_u1.y >> 16); \
  } while (0)

#pragma unroll
  for (int p = 0; p < 4; ++p) LOADCOL(win[p], x0c + p);

  bf16_t* arow = attn + ((size_t)b * NN + s * 256) * NC + h * HD + d;
#pragma unroll
  for (int i = 0; i < 8; ++i) {
    int x = x0c + i;
    LOADCOL(win[4], x + 4);
#pragma unroll
    for (int ty = 0; ty < 4; ++ty) {
      float acc = bd;
#pragma unroll
      for (int ky = 0; ky < 5; ++ky)
#pragma unroll
        for (int kx = 0; kx < 5; ++kx)
          acc += wr[ky * 5 + kx] * win[kx][ty + ky];
      int tl = ty * 64 + x;
      acc += bf2f(mvz[tl * 32 + d]);
      arow[(size_t)tl * NC] = f2bf(acc);
    }
#pragma unroll
    for (int c2 = 0; c2 < 4; ++c2)
#pragma unroll
      for (int r2 = 0; r2 < 8; ++r2) win[c2][r2] = win[c2 + 1][r2];
  }
#undef LOADCOL
}

// ---------------------------------------------------------------------------
// Kernel 6: output projection via bf16 MFMA, 128x256 tile, 512 threads
// (8 waves, 2m x 4n), BK=64. attn A-tile is read ONCE (grid y collapsed:
// was (512,2) x 128-wide-N = 67MB A-reads; now 33.5MB). Same 128B-row XOR
// swizzle (row&7 == fm&7 identities preserved). fp32 float4 token-
// contiguous store epilogue unchanged.
// ---------------------------------------------------------------------------
__global__ __launch_bounds__(512) void k_proj_mfma(
    const bf16_t* __restrict__ attn, const bf16_t* __restrict__ Wpb,
    const float* __restrict__ bp, float* __restrict__ out)
{
  __shared__ bf16_t As[128 * 64];   // 16 KB
  __shared__ bf16_t Bs[256 * 64];   // 32 KB
  const int tid = threadIdx.x;
  const int lane = tid & 63;
  const int w = tid >> 6;           // 0..7
  const size_t m0 = (size_t)blockIdx.x * 128;
  const bf16_t* Ab = attn + m0 * NC;
  const bf16_t* Bb = Wpb;

  const int wm = (w & 1) * 64;
  const int wn = (w >> 1) * 64;
  const int rowi = lane >> 3;                   // row within 8-row stage instr
  const int schunk = ((lane & 7) ^ rowi) * 8;   // pre-swizzled source chunk
  const int fm = lane & 15;
  const int kg = lane >> 4;
  const int f7 = fm & 7;

  floatx4 acc[4][4];
#pragma unroll
  for (int i = 0; i < 4; ++i)
#pragma unroll
    for (int j = 0; j < 4; ++j) {
      floatx4 z = {0.f, 0.f, 0.f, 0.f};
      acc[i][j] = z;
    }

  for (int k0 = 0; k0 < NC; k0 += 64) {
    // A: 128 rows over 8 waves = 16 rows/wave = 2 stage instrs
#pragma unroll
    for (int i = 0; i < 2; ++i)
      gl_lds16(Ab + (size_t)(w * 16 + i * 8 + rowi) * NC + k0 + schunk,
               &As[(w * 16 + i * 8) * 64]);
    // B: 256 rows over 8 waves = 32 rows/wave = 4 stage instrs
#pragma unroll
    for (int i = 0; i < 4; ++i)
      gl_lds16(Bb + (size_t)(w * 32 + i * 8 + rowi) * NC + k0 + schunk,
               &Bs[(w * 32 + i * 8) * 64]);
    __syncthreads();
#pragma unroll
    for (int h = 0; h < 2; ++h) {
      const int rofs = (((h << 2) | kg) ^ f7) * 8;
      shortx8 af[4], bfg[4];
#pragma unroll
      for (int t = 0; t < 4; ++t) {
        af[t]  = *(const shortx8*)&As[(wm + t * 16 + fm) * 64 + rofs];
        bfg[t] = *(const shortx8*)&Bs[(wn + t * 16 + fm) * 64 + rofs];
      }
#pragma unroll
      for (int tm = 0; tm < 4; ++tm)
#pragma unroll
        for (int tn = 0; tn < 4; ++tn)
          acc[tm][tn] = __builtin_amdgcn_mfma_f32_16x16x32_bf16(
              af[tm], bfg[tn], acc[tm][tn], 0, 0, 0);
    }
    __syncthreads();
  }

  const int b = (int)(m0 >> 12);
  const int t0 = (int)(m0 & 4095);
  float* ob = out + (size_t)b * NC * NN;
#pragma unroll
  for (int tn = 0; tn < 4; ++tn) {
    int j = wn + tn * 16 + fm;
    float bj = bp[j];
#pragma unroll
    for (int tm = 0; tm < 4; ++tm) {
      int trow = t0 + wm + tm * 16 + kg * 4;
      float4 o;
      o.x = acc[tm][tn][0] + bj;
      o.y = acc[tm][tn][1] + bj;
      o.z = acc[tm][tn][2] + bj;
      o.w = acc[tm][tn][3] + bj;
      *(float4*)(ob + (size_t)j * NN + trow) = o;
    }
  }
}

// ---------------------------------------------------------------------------
extern "C" void kernel_launch(void* const* d_in, const int* in_sizes, int n_in,
                              void* d_out, int out_size, void* d_ws, size_t ws_size,
                              hipStream_t stream)
{
  (void)in_sizes; (void)n_in; (void)out_size; (void)ws_size;
  const float* x    = (const float*)d_in[0];
  const float* Wq   = (const float*)d_in[1];
  const float* bq   = (const float*)d_in[2];
  const float* Wkv  = (const float*)d_in[3];
  const float* bkv  = (const float*)d_in[4];
  const float* Wp   = (const float*)d_in[5];
  const float* bp   = (const float*)d_in[6];
  const float* dwcw = (const float*)d_in[7];
  const float* dwcb = (const float*)d_in[8];
  const float* sp   = (const float*)d_in[9];
  float* out = (float*)d_out;

  char* wsb = (char*)d_ws;
  bf16_t* qkv  = (bf16_t*)wsb;                            // 100,663,296 B
  bf16_t* attn = (bf16_t*)(wsb + 100663296u);             // 33,554,432 B
  bf16_t* xbf  = attn;                                    // alias (disjoint lifetimes)
  float*  kvsp  = (float*)attn;                           // 4,194,304 B (aliases attn)
  float*  ksump = (float*)(wsb + 100663296u + 16777216u); // 131,072 B
  char*   tail  = wsb + 100663296u + 33554432u + 2097152u + 65536u;
  bf16_t* kvTb  = (bf16_t*)tail;                          // 262,144 B
  bf16_t* ksumb = kvTb + (size_t)BHD * HD * HD;           // 8,192 B
  bf16_t* Wqkvb = ksumb + (size_t)BHD * HD;               // 393,216 B
  bf16_t* Wpb   = Wqkvb + 768 * 256;                      // 131,072 B
  float*  bias768 = (float*)(Wpb + 256 * 256);
  float*  rscale  = bias768 + 768;

  k_prepx<<<dim3(64, 4, 16), 256, 0, stream>>>(x, xbf);
  k_prepw<<<1026, 256, 0, stream>>>(Wq, Wkv, Wp, bq, bkv, sp, Wqkvb, Wpb, bias768, rscale);
  k_qkv_mfma<<<dim3(64, 3, 16), 256, 0, stream>>>(xbf, Wqkvb, bias768, rscale, qkv);
  k_kvstate<<<dim3(BHD, KRED), 256, 0, stream>>>(qkv, kvsp, ksump);
  k_combine<<<512, 256, 0, stream>>>(kvsp, ksump, kvTb, ksumb);
  k_attnout<<<dim3(16, BHD), 256, 0, stream>>>(qkv, kvTb, ksumb, dwcw, dwcb, attn);
  k_proj_mfma<<<dim3(512), 512, 0, stream>>>(attn, Wpb, bp, out);
}